// Round 1
// baseline (677.755 us; speedup 1.0000x reference)
//
#include <hip/hip_runtime.h>

typedef unsigned short u16;
typedef __attribute__((ext_vector_type(4))) float floatx4;
typedef __attribute__((ext_vector_type(8))) __bf16 bf16x8;
typedef __attribute__((ext_vector_type(4))) unsigned short ushort4v;

#define DI __device__ __forceinline__

// ---- problem constants ----
// B=8, C=512, T=1024, H=8, F=2048, KS=3, head dim 64, ROPE_D=32, EPS=1e-4

DI u16 f2bf(float f) {
  union { float f; unsigned u; } v; v.f = f;
  unsigned r = v.u + 0x7fffu + ((v.u >> 16) & 1u);
  return (u16)(r >> 16);
}
DI float bf2f(u16 h) {
  union { unsigned u; float f; } v; v.u = ((unsigned)h) << 16;
  return v.f;
}

#define GLDS(g, l) __builtin_amdgcn_global_load_lds( \
    (const __attribute__((address_space(1))) unsigned int*)(g), \
    (__attribute__((address_space(3))) unsigned int*)(l), 16, 0, 0)

// ---------------------------------------------------------------------------
// Generic bf16 MFMA GEMM, gemm_bt form: A (M x K) row-major, Bt (N x K) row-major.
// BM=128, BK=32, 256 threads = 4 waves in 2x2 grid; per-wave 64 x (BN/2) output,
// 4 x FN frags of 16x16, one 16x16x32 MFMA k-step per BK tile.
// MODE epilogues: 0=QKV(+bias+rope+scatter) 1=scores(scale+mask) 2=PV(write o^T)
//                 3=oproj(+bias) 4=conv1(+bias+relu, write h1^T) 5=conv2(+bias,*mask)
// ---------------------------------------------------------------------------
template<int MODE, int BN>
__global__ __launch_bounds__(256) void k_gemm(
    const u16* __restrict__ A, int lda, long long sAz,
    const u16* __restrict__ Bt, int ldb, long long sBz,
    int K,
    u16* __restrict__ o0, u16* __restrict__ o1, u16* __restrict__ o2,
    const float* __restrict__ bias,
    const float* __restrict__ ctab, const float* __restrict__ stab,
    const float* __restrict__ msk)
{
  constexpr int BM = 128, BK = 32;
  constexpr int FN = BN / 32;
  __shared__ __align__(16) u16 As[BM * BK];
  __shared__ __align__(16) u16 Bs[BN * BK];

  const int tid  = threadIdx.x;
  const int wave = tid >> 6, lane = tid & 63;
  const int wm = wave >> 1, wn = wave & 1;
  const int lr = lane & 15, kg = lane >> 4;
  const int m0 = blockIdx.x * BM, n0 = blockIdx.y * BN;
  const int z  = blockIdx.z;
  const u16* Ab = A  + (size_t)z * sAz;
  const u16* Bb = Bt + (size_t)z * sBz;

  floatx4 acc[4][FN];
#pragma unroll
  for (int i = 0; i < 4; ++i)
#pragma unroll
    for (int j = 0; j < FN; ++j) acc[i][j] = (floatx4){0.f, 0.f, 0.f, 0.f};

  for (int k0 = 0; k0 < K; k0 += BK) {
#pragma unroll
    for (int ch = 0; ch < (BM * BK / 8) / 256; ++ch) {
      int idx = ch * 256 + tid;
      int row = idx >> 2, kk = (idx & 3) << 3;
      GLDS(Ab + (size_t)(m0 + row) * lda + (k0 + kk), &As[idx * 8]);
    }
#pragma unroll
    for (int ch = 0; ch < (BN * BK / 8) / 256; ++ch) {
      int idx = ch * 256 + tid;
      int row = idx >> 2, kk = (idx & 3) << 3;
      GLDS(Bb + (size_t)(n0 + row) * ldb + (k0 + kk), &Bs[idx * 8]);
    }
    __syncthreads();
    bf16x8 af[4], bfr[FN];
#pragma unroll
    for (int i = 0; i < 4; ++i)
      af[i] = *(const bf16x8*)&As[(wm * 64 + i * 16 + lr) * BK + kg * 8];
#pragma unroll
    for (int j = 0; j < FN; ++j)
      bfr[j] = *(const bf16x8*)&Bs[(wn * (BN / 2) + j * 16 + lr) * BK + kg * 8];
#pragma unroll
    for (int i = 0; i < 4; ++i)
#pragma unroll
      for (int j = 0; j < FN; ++j)
        acc[i][j] = __builtin_amdgcn_mfma_f32_16x16x32_bf16(af[i], bfr[j], acc[i][j], 0, 0, 0);
    __syncthreads();
  }

  const int wrow0 = m0 + wm * 64;          // wave's first output row (64-aligned)
  const int col0  = n0 + wn * (BN / 2);    // wave's first output col

  if constexpr (MODE == 0) {  // ---- QKV: bias + RoPE + scatter to q/k/v ----
    float v[4][FN][4];
#pragma unroll
    for (int i = 0; i < 4; ++i)
#pragma unroll
      for (int j = 0; j < FN; ++j)
#pragma unroll
        for (int r = 0; r < 4; ++r)
          v[i][j][r] = acc[i][j][r] + bias[wrow0 + i * 16 + kg * 4 + r];
    const int sec = wrow0 >> 9;            // 0=q 1=k 2=v
    const int hh  = (wrow0 & 511) >> 6;    // head
    if (sec < 2) {
      // rotate-half over dk pairs (frag0 <-> frag1 share angle theta_{dk&15})
#pragma unroll
      for (int j = 0; j < FN; ++j) {
        const int t = col0 + j * 16 + lr;
#pragma unroll
        for (int r = 0; r < 4; ++r) {
          const int a = kg * 4 + r;
          const float cv = ctab[t * 16 + a], sv = stab[t * 16 + a];
          const float a0 = v[0][j][r], a1 = v[1][j][r];
          v[0][j][r] = a0 * cv - a1 * sv;
          v[1][j][r] = a1 * cv + a0 * sv;
        }
      }
      u16* dst = (sec == 0) ? o0 : o1;     // q,k: (B,H,T,64)
#pragma unroll
      for (int i = 0; i < 4; ++i)
#pragma unroll
        for (int j = 0; j < FN; ++j) {
          const int t = col0 + j * 16 + lr;
          ushort4v pk;
#pragma unroll
          for (int r = 0; r < 4; ++r) pk[r] = f2bf(v[i][j][r]);
          *(ushort4v*)&dst[(((size_t)z * 8 + hh) * 1024 + t) * 64 + i * 16 + kg * 4] = pk;
        }
    } else {                               // v: (B,H,64,T)
#pragma unroll
      for (int i = 0; i < 4; ++i)
#pragma unroll
        for (int j = 0; j < FN; ++j) {
          const int t = col0 + j * 16 + lr;
#pragma unroll
          for (int r = 0; r < 4; ++r) {
            const int dk = i * 16 + kg * 4 + r;
            o2[(((size_t)z * 8 + hh) * 64 + dk) * 1024 + t] = f2bf(v[i][j][r]);
          }
        }
    }
  } else if constexpr (MODE == 1) {  // ---- scores: *1/8, mask, bf16 ----
    const int bb = z >> 3;
#pragma unroll
    for (int i = 0; i < 4; ++i)
#pragma unroll
      for (int j = 0; j < FN; ++j) {
        const int cc = col0 + j * 16 + lr;
#pragma unroll
        for (int r = 0; r < 4; ++r) {
          const int rr = wrow0 + i * 16 + kg * 4 + r;
          float sv = acc[i][j][r] * 0.125f;
          if (msk[((size_t)bb * 1024 + rr) * 1024 + cc] == 0.f) sv = -10000.f;
          o0[((size_t)z * 1024 + rr) * 1024 + cc] = f2bf(sv);
        }
      }
  } else if constexpr (MODE == 2) {  // ---- PV: write o^T (B,T,C) ----
    const int bb = z >> 3, hh = z & 7;
#pragma unroll
    for (int i = 0; i < 4; ++i)
#pragma unroll
      for (int j = 0; j < FN; ++j) {
        const int dk = col0 + j * 16 + lr;
#pragma unroll
        for (int r = 0; r < 4; ++r) {
          const int t = wrow0 + i * 16 + kg * 4 + r;
          o0[((size_t)bb * 1024 + t) * 512 + hh * 64 + dk] = f2bf(acc[i][j][r]);
        }
      }
  } else if constexpr (MODE == 3) {  // ---- O-proj: +bias, y1 (B,C,T) ----
#pragma unroll
    for (int i = 0; i < 4; ++i)
#pragma unroll
      for (int j = 0; j < FN; ++j) {
        const int cc = col0 + j * 16 + lr;
#pragma unroll
        for (int r = 0; r < 4; ++r) {
          const int rr = wrow0 + i * 16 + kg * 4 + r;
          o0[((size_t)z * 512 + rr) * 1024 + cc] = f2bf(acc[i][j][r] + bias[rr]);
        }
      }
  } else if constexpr (MODE == 4) {  // ---- conv1: +bias, relu, h1^T (B,T,F) ----
#pragma unroll
    for (int i = 0; i < 4; ++i) {
      const int r0 = wrow0 + i * 16 + kg * 4;
#pragma unroll
      for (int j = 0; j < FN; ++j) {
        const int cc = col0 + j * 16 + lr;
        ushort4v pk;
#pragma unroll
        for (int r = 0; r < 4; ++r) pk[r] = f2bf(fmaxf(acc[i][j][r] + bias[r0 + r], 0.f));
        *(ushort4v*)&o0[((size_t)z * 1024 + cc) * 2048 + r0] = pk;
      }
    }
  } else {                           // ---- conv2: +bias, *x_mask, y2 (B,C,T) ----
#pragma unroll
    for (int i = 0; i < 4; ++i)
#pragma unroll
      for (int j = 0; j < FN; ++j) {
        const int cc = col0 + j * 16 + lr;
        const float mv = msk[(size_t)z * 1024 + cc];
#pragma unroll
        for (int r = 0; r < 4; ++r) {
          const int rr = wrow0 + i * 16 + kg * 4 + r;
          o0[((size_t)z * 512 + rr) * 1024 + cc] = f2bf((acc[i][j][r] + bias[rr]) * mv);
        }
      }
  }
}

// ---------------------------------------------------------------------------
// small glue kernels
// ---------------------------------------------------------------------------
__global__ __launch_bounds__(256) void k_cvt(const float* __restrict__ in, u16* __restrict__ out, int n) {
  int i = blockIdx.x * 256 + threadIdx.x;
  if (i < n) out[i] = f2bf(in[i]);
}

__global__ __launch_bounds__(256) void k_repack_w1(const float* __restrict__ in, u16* __restrict__ out) {
  int i = blockIdx.x * 256 + threadIdx.x;          // over 2048*1536
  int f = i / 1536, rem = i % 1536;
  int kk = rem >> 9, c = rem & 511;                // out (F, KS, C)
  out[i] = f2bf(in[f * 1536 + c * 3 + kk]);
}

__global__ __launch_bounds__(256) void k_repack_w2(const float* __restrict__ in, u16* __restrict__ out) {
  int i = blockIdx.x * 256 + threadIdx.x;          // over 512*6144
  int c = i / 6144, rem = i % 6144;
  int kk = rem >> 11, f = rem & 2047;              // out (C, KS, F)
  out[i] = f2bf(in[c * 6144 + f * 3 + kk]);
}

__global__ __launch_bounds__(256) void k_bias_concat(const float* __restrict__ bq, const float* __restrict__ bk,
                                                     const float* __restrict__ bv, float* __restrict__ out) {
  int i = blockIdx.x * 256 + threadIdx.x;
  if (i < 512) out[i] = bq[i];
  else if (i < 1024) out[i] = bk[i - 512];
  else if (i < 1536) out[i] = bv[i - 1024];
}

__global__ __launch_bounds__(256) void k_rope_tables(float* __restrict__ ct, float* __restrict__ st) {
  int i = blockIdx.x * 256 + threadIdx.x;          // 1024*16
  int t = i >> 4, a = i & 15;
  float theta = powf(10000.f, -(float)a / 16.f);
  float ang = (float)t * theta;
  ct[i] = cosf(ang);
  st[i] = sinf(ang);
}

// tiled fp32 (B,R,TT) -> bf16 (B,TT,R) transpose-convert, optional column mask
__global__ __launch_bounds__(256) void k_tcvt(const float* __restrict__ in, u16* __restrict__ out,
                                              const float* __restrict__ msk, int R, int TT) {
  __shared__ u16 tile[64][65];
  const int b = blockIdx.z;
  const int r0 = blockIdx.x * 64, t0 = blockIdx.y * 64;
  const int tx = threadIdx.x & 63, ty = threadIdx.x >> 6;
  const float mv = msk ? msk[(size_t)b * TT + t0 + tx] : 1.f;
  const float* ib = in + (size_t)b * R * TT;
#pragma unroll
  for (int rr = ty; rr < 64; rr += 4)
    tile[rr][tx] = f2bf(ib[(size_t)(r0 + rr) * TT + t0 + tx] * mv);
  __syncthreads();
  u16* ob = out + (size_t)b * TT * R;
#pragma unroll
  for (int tt = ty; tt < 64; tt += 4)
    ob[(size_t)(t0 + tt) * R + r0 + tx] = tile[tx][tt];
}

// build (B,T, 3*Fin) im2col rows from (B,T,Fin) source, zero-padded, optional row mask
__global__ __launch_bounds__(256) void k_im2colT(const u16* __restrict__ src, u16* __restrict__ dst,
                                                 const float* __restrict__ msk, int Fin) {
  const int t = blockIdx.x, b = blockIdx.y;
  u16* orow = dst + ((size_t)b * 1024 + t) * (3 * Fin);
  for (int kk = 0; kk < 3; ++kk) {
    const int ts = t + kk - 1;
    const bool ok = ((unsigned)ts) < 1024u;
    const u16* srow = src + ((size_t)b * 1024 + ts) * Fin;
    float mv = ok ? (msk ? msk[(size_t)b * 1024 + ts] : 1.f) : 0.f;
    ushort4v* op = (ushort4v*)(orow + kk * Fin);
    if (!ok || mv == 0.f) {
      ushort4v zz = (ushort4v)0;
      for (int i = threadIdx.x; i < Fin / 4; i += 256) op[i] = zz;
    } else if (mv == 1.f) {
      const ushort4v* ip = (const ushort4v*)srow;
      for (int i = threadIdx.x; i < Fin / 4; i += 256) op[i] = ip[i];
    } else {
      const ushort4v* ip = (const ushort4v*)srow;
      for (int i = threadIdx.x; i < Fin / 4; i += 256) {
        ushort4v a = ip[i], o;
#pragma unroll
        for (int q = 0; q < 4; ++q) o[q] = f2bf(bf2f(a[q]) * mv);
        op[i] = o;
      }
    }
  }
}

// in-place row softmax on bf16 scores; one block per row of 1024
__global__ __launch_bounds__(256) void k_softmax(u16* __restrict__ s) {
  const size_t base = (size_t)blockIdx.x * 1024;
  const int tid = threadIdx.x, lane = tid & 63, wv = tid >> 6;
  ushort4v u = *(const ushort4v*)&s[base + tid * 4];
  float v0 = bf2f(u[0]), v1 = bf2f(u[1]), v2 = bf2f(u[2]), v3 = bf2f(u[3]);
  float mx = fmaxf(fmaxf(v0, v1), fmaxf(v2, v3));
#pragma unroll
  for (int o = 32; o; o >>= 1) mx = fmaxf(mx, __shfl_xor(mx, o));
  __shared__ float rmax[4], rsum[4];
  if (lane == 0) rmax[wv] = mx;
  __syncthreads();
  mx = fmaxf(fmaxf(rmax[0], rmax[1]), fmaxf(rmax[2], rmax[3]));
  const float L2E = 1.44269504f;
  float e0 = exp2f((v0 - mx) * L2E), e1 = exp2f((v1 - mx) * L2E);
  float e2 = exp2f((v2 - mx) * L2E), e3 = exp2f((v3 - mx) * L2E);
  float sm = e0 + e1 + e2 + e3;
#pragma unroll
  for (int o = 32; o; o >>= 1) sm += __shfl_xor(sm, o);
  if (lane == 0) rsum[wv] = sm;
  __syncthreads();
  sm = rsum[0] + rsum[1] + rsum[2] + rsum[3];
  const float inv = 1.f / sm;
  ushort4v p;
  p[0] = f2bf(e0 * inv); p[1] = f2bf(e1 * inv); p[2] = f2bf(e2 * inv); p[3] = f2bf(e3 * inv);
  *(ushort4v*)&s[base + tid * 4] = p;
}

// layernorm over C=512 at each (b,t); xin fp32 (B,C,T) [*mask], + ybf bf16 (B,C,T)
// blocks (B, T/64), 256 thr = 64 t-lanes x 4 c-groups
__global__ __launch_bounds__(256) void k_ln(const float* __restrict__ xin, const u16* __restrict__ ybf,
                                            const float* __restrict__ xm, const float* __restrict__ g,
                                            const float* __restrict__ be, float* __restrict__ xout) {
  const int b = blockIdx.x;
  const int tx = threadIdx.x & 63, ty = threadIdx.x >> 6;
  const int t = blockIdx.y * 64 + tx;
  const float m = xm ? xm[(size_t)b * 1024 + t] : 1.f;
  const size_t base = (size_t)b * 512 * 1024 + t;
  float sum = 0.f, ss = 0.f;
  for (int c = ty; c < 512; c += 4) {
    float r = xin[base + (size_t)c * 1024] * m + bf2f(ybf[base + (size_t)c * 1024]);
    sum += r; ss += r * r;
  }
  __shared__ float S[4][64], Q[4][64];
  S[ty][tx] = sum; Q[ty][tx] = ss;
  __syncthreads();
  sum = S[0][tx] + S[1][tx] + S[2][tx] + S[3][tx];
  ss  = Q[0][tx] + Q[1][tx] + Q[2][tx] + Q[3][tx];
  const float mean = sum * (1.f / 512.f);
  const float var  = ss * (1.f / 512.f) - mean * mean;
  const float rs   = rsqrtf(var + 1e-4f);
  for (int c = ty; c < 512; c += 4) {
    float r = xin[base + (size_t)c * 1024] * m + bf2f(ybf[base + (size_t)c * 1024]);
    xout[base + (size_t)c * 1024] = (r - mean) * rs * g[c] + be[c];
  }
}

// ---------------------------------------------------------------------------
extern "C" void kernel_launch(void* const* d_in, const int* in_sizes, int n_in,
                              void* d_out, int out_size, void* d_ws, size_t ws_size,
                              hipStream_t stream) {
  (void)in_sizes; (void)n_in; (void)out_size; (void)ws_size;
  const float* x   = (const float*)d_in[0];
  const float* xm  = (const float*)d_in[1];
  const float* am  = (const float*)d_in[2];
  const float* wq  = (const float*)d_in[3];
  const float* bq  = (const float*)d_in[4];
  const float* wk  = (const float*)d_in[5];
  const float* bk  = (const float*)d_in[6];
  const float* wv  = (const float*)d_in[7];
  const float* bv  = (const float*)d_in[8];
  const float* wo  = (const float*)d_in[9];
  const float* bo  = (const float*)d_in[10];
  const float* w1  = (const float*)d_in[11];
  const float* b1  = (const float*)d_in[12];
  const float* w2  = (const float*)d_in[13];
  const float* b2  = (const float*)d_in[14];
  const float* g1  = (const float*)d_in[15];
  const float* be1 = (const float*)d_in[16];
  const float* g2  = (const float*)d_in[17];
  const float* be2 = (const float*)d_in[18];
  float* out = (float*)d_out;

  char* ws = (char*)d_ws;
  size_t off = 0;
  auto alloc = [&](size_t bytes) { char* p = ws + off; off += (bytes + 255) & ~(size_t)255; return p; };

  u16*   wqkv = (u16*)  alloc((size_t)1536 * 512 * 2);
  u16*   wob  = (u16*)  alloc((size_t)512 * 512 * 2);
  u16*   w1p  = (u16*)  alloc((size_t)2048 * 1536 * 2);
  u16*   w2p  = (u16*)  alloc((size_t)512 * 6144 * 2);
  float* bqkv = (float*)alloc(1536 * 4);
  float* ctab = (float*)alloc(1024 * 16 * 4);
  float* stab = (float*)alloc(1024 * 16 * 4);
  float* X2   = (float*)alloc((size_t)8 * 512 * 1024 * 4);   // LN1 output fp32
  u16*   x2bT = (u16*)  alloc((size_t)8 * 1024 * 512 * 2);   // LN1 out, transposed bf16 (masked)
  u16*   h1T  = (u16*)  alloc((size_t)8 * 1024 * 2048 * 2);  // conv1 out (B,T,F)
  u16*   y    = (u16*)  alloc((size_t)8 * 512 * 1024 * 2);   // y1 then y2 (B,C,T)
  u16*   xbT  = (u16*)  alloc((size_t)8 * 1024 * 512 * 2);   // masked x^T; reused as o^T
  u16*   qkv3 = (u16*)  alloc((size_t)3 * 8 * 8 * 1024 * 64 * 2); // q,k,v; reused as conv1 im2col
  u16*   sb   = (u16*)  alloc((size_t)8 * 8 * 1024 * 1024 * 2);   // scores/p; reused as conv2 im2col

  u16* qb   = qkv3;
  u16* kb   = qkv3 + (size_t)8 * 8 * 1024 * 64;
  u16* vb   = kb   + (size_t)8 * 8 * 1024 * 64;
  u16* oT   = xbT;
  u16* xc1T = qkv3;
  u16* xc2T = sb;

  dim3 blk(256);

  // weight/bias/table prep
  k_cvt<<<dim3(1024), blk, 0, stream>>>(wq, wqkv, 512 * 512);
  k_cvt<<<dim3(1024), blk, 0, stream>>>(wk, wqkv + 512 * 512, 512 * 512);
  k_cvt<<<dim3(1024), blk, 0, stream>>>(wv, wqkv + 2 * 512 * 512, 512 * 512);
  k_cvt<<<dim3(1024), blk, 0, stream>>>(wo, wob, 512 * 512);
  k_repack_w1<<<dim3(12288), blk, 0, stream>>>(w1, w1p);
  k_repack_w2<<<dim3(12288), blk, 0, stream>>>(w2, w2p);
  k_bias_concat<<<dim3(6), blk, 0, stream>>>(bq, bk, bv, bqkv);
  k_rope_tables<<<dim3(64), blk, 0, stream>>>(ctab, stab);

  // x^T (masked, bf16)
  k_tcvt<<<dim3(8, 16, 8), blk, 0, stream>>>(x, xbT, xm, 512, 1024);

  // QKV projection + bias + rope + head scatter
  k_gemm<0, 128><<<dim3(12, 8, 8), blk, 0, stream>>>(
      wqkv, 512, 0, xbT, 512, 512 * 1024, 512, qb, kb, vb, bqkv, ctab, stab, nullptr);

  // scores = q k^T / 8 (+ mask), bf16
  k_gemm<1, 128><<<dim3(8, 8, 64), blk, 0, stream>>>(
      qb, 64, 65536, kb, 64, 65536, 64, sb, nullptr, nullptr, nullptr, nullptr, nullptr, am);

  // softmax rows in place
  k_softmax<<<dim3(65536), blk, 0, stream>>>(sb);

  // o = p v, written as o^T (B,T,C)
  k_gemm<2, 64><<<dim3(8, 1, 64), blk, 0, stream>>>(
      sb, 1024, 1048576, vb, 1024, 65536, 1024, oT, nullptr, nullptr, nullptr, nullptr, nullptr, nullptr);

  // y1 = wo o + bo (B,C,T)
  k_gemm<3, 128><<<dim3(4, 8, 8), blk, 0, stream>>>(
      wob, 512, 0, oT, 512, 512 * 1024, 512, y, nullptr, nullptr, bo, nullptr, nullptr, nullptr);

  // LN1: X2 = ln(x*mask + y1)
  k_ln<<<dim3(8, 16), blk, 0, stream>>>(x, y, xm, g1, be1, X2);

  // conv path
  k_tcvt<<<dim3(8, 16, 8), blk, 0, stream>>>(X2, x2bT, xm, 512, 1024);
  k_im2colT<<<dim3(1024, 8), blk, 0, stream>>>(x2bT, xc1T, nullptr, 512);
  k_gemm<4, 128><<<dim3(16, 8, 8), blk, 0, stream>>>(
      w1p, 1536, 0, xc1T, 1536, (long long)1024 * 1536, 1536, h1T, nullptr, nullptr, b1, nullptr, nullptr, nullptr);
  k_im2colT<<<dim3(1024, 8), blk, 0, stream>>>(h1T, xc2T, xm, 2048);
  k_gemm<5, 128><<<dim3(4, 8, 8), blk, 0, stream>>>(
      w2p, 6144, 0, xc2T, 6144, (long long)1024 * 6144, 6144, y, nullptr, nullptr, b2, nullptr, nullptr, xm);

  // LN2 -> out
  k_ln<<<dim3(8, 16), blk, 0, stream>>>(X2, y, nullptr, g2, be2, out);
}

// Round 2
// 586.919 us; speedup vs baseline: 1.1548x; 1.1548x over previous
//
#include <hip/hip_runtime.h>

typedef unsigned short u16;
typedef __attribute__((ext_vector_type(4))) float floatx4;
typedef __attribute__((ext_vector_type(8))) __bf16 bf16x8;
typedef __attribute__((ext_vector_type(4))) unsigned short ushort4v;

#define DI __device__ __forceinline__

// ---- problem constants ----
// B=8, C=512, T=1024, H=8, F=2048, KS=3, head dim 64, ROPE_D=32, EPS=1e-4

DI u16 f2bf(float f) {
  union { float f; unsigned u; } v; v.f = f;
  unsigned r = v.u + 0x7fffu + ((v.u >> 16) & 1u);
  return (u16)(r >> 16);
}
DI float bf2f(u16 h) {
  union { unsigned u; float f; } v; v.u = ((unsigned)h) << 16;
  return v.f;
}

#define GLDS(g, l) __builtin_amdgcn_global_load_lds( \
    (const __attribute__((address_space(1))) unsigned int*)(g), \
    (__attribute__((address_space(3))) unsigned int*)(l), 16, 0, 0)

// ---------------------------------------------------------------------------
// Batched bf16 MFMA GEMM (z = batch*head), gemm_bt form.
// MODE 1 = scores (scale+mask, bf16 out), MODE 2 = PV (write o^T (B,T,C))
// ---------------------------------------------------------------------------
template<int MODE, int BN>
__global__ __launch_bounds__(256) void k_gemm(
    const u16* __restrict__ A, int lda, long long sAz,
    const u16* __restrict__ Bt, int ldb, long long sBz,
    int K,
    u16* __restrict__ o0,
    const float* __restrict__ msk)
{
  constexpr int BM = 128, BK = 32;
  constexpr int FN = BN / 32;
  __shared__ __align__(16) u16 As[BM * BK];
  __shared__ __align__(16) u16 Bs[BN * BK];

  const int tid  = threadIdx.x;
  const int wave = tid >> 6, lane = tid & 63;
  const int wm = wave >> 1, wn = wave & 1;
  const int lr = lane & 15, kg = lane >> 4;
  const int m0 = blockIdx.x * BM, n0 = blockIdx.y * BN;
  const int z  = blockIdx.z;
  const u16* Ab = A  + (size_t)z * sAz;
  const u16* Bb = Bt + (size_t)z * sBz;

  floatx4 acc[4][FN];
#pragma unroll
  for (int i = 0; i < 4; ++i)
#pragma unroll
    for (int j = 0; j < FN; ++j) acc[i][j] = (floatx4){0.f, 0.f, 0.f, 0.f};

  for (int k0 = 0; k0 < K; k0 += BK) {
#pragma unroll
    for (int ch = 0; ch < (BM * BK / 8) / 256; ++ch) {
      int idx = ch * 256 + tid;
      int row = idx >> 2, kk = (idx & 3) << 3;
      GLDS(Ab + (size_t)(m0 + row) * lda + (k0 + kk), &As[idx * 8]);
    }
#pragma unroll
    for (int ch = 0; ch < (BN * BK / 8) / 256; ++ch) {
      int idx = ch * 256 + tid;
      int row = idx >> 2, kk = (idx & 3) << 3;
      GLDS(Bb + (size_t)(n0 + row) * ldb + (k0 + kk), &Bs[idx * 8]);
    }
    __syncthreads();
    bf16x8 af[4], bfr[FN];
#pragma unroll
    for (int i = 0; i < 4; ++i)
      af[i] = *(const bf16x8*)&As[(wm * 64 + i * 16 + lr) * BK + kg * 8];
#pragma unroll
    for (int j = 0; j < FN; ++j)
      bfr[j] = *(const bf16x8*)&Bs[(wn * (BN / 2) + j * 16 + lr) * BK + kg * 8];
#pragma unroll
    for (int i = 0; i < 4; ++i)
#pragma unroll
      for (int j = 0; j < FN; ++j)
        acc[i][j] = __builtin_amdgcn_mfma_f32_16x16x32_bf16(af[i], bfr[j], acc[i][j], 0, 0, 0);
    __syncthreads();
  }

  const int wrow0 = m0 + wm * 64;
  const int col0  = n0 + wn * (BN / 2);

  if constexpr (MODE == 1) {  // ---- scores: *1/8, mask, bf16 ----
    const int bb = z >> 3;
#pragma unroll
    for (int i = 0; i < 4; ++i)
#pragma unroll
      for (int j = 0; j < FN; ++j) {
        const int cc = col0 + j * 16 + lr;
#pragma unroll
        for (int r = 0; r < 4; ++r) {
          const int rr = wrow0 + i * 16 + kg * 4 + r;
          float sv = acc[i][j][r] * 0.125f;
          if (msk[((size_t)bb * 1024 + rr) * 1024 + cc] == 0.f) sv = -10000.f;
          o0[((size_t)z * 1024 + rr) * 1024 + cc] = f2bf(sv);
        }
      }
  } else {                    // ---- PV: write o^T (B,T,C) ----
    const int bb = z >> 3, hh = z & 7;
#pragma unroll
    for (int i = 0; i < 4; ++i)
#pragma unroll
      for (int j = 0; j < FN; ++j) {
        const int dk = col0 + j * 16 + lr;
#pragma unroll
        for (int r = 0; r < 4; ++r) {
          const int t = wrow0 + i * 16 + kg * 4 + r;
          o0[((size_t)bb * 1024 + t) * 512 + hh * 64 + dk] = f2bf(acc[i][j][r]);
        }
      }
  }
}

// ---------------------------------------------------------------------------
// Flat GEMM (batch folded into N=8192), gemm_bt form, XCD-swizzled blocks.
// A (M x K) row-major (lda == K).  B addressing:
//   TAPK == 0 : Bt row bt, ldb == K
//   TAPK > 0  : conv tap mode — B[bt, k] = Bpad[b, t + k/TAPK, k%TAPK], where
//               Bpad is (B, 1026, TAPK) zero-padded at rows 0 and 1025.
// MODE 0=QKV(+bias+rope+scatter) 3=oproj(+bias) 4=conv1(relu*mask -> padded h1)
// MODE 5=conv2(+bias,*mask)
// ---------------------------------------------------------------------------
template<int MODE, int BN, int TAPK>
__global__ __launch_bounds__(256) void k_cgemm(
    const u16* __restrict__ A,
    const u16* __restrict__ Bsrc,
    int K,
    u16* __restrict__ o0, u16* __restrict__ o1, u16* __restrict__ o2,
    const float* __restrict__ bias,
    const float* __restrict__ ctab, const float* __restrict__ stab,
    const float* __restrict__ msk)
{
  constexpr int BM = 128, BK = 32;
  constexpr int FN = BN / 32;
  __shared__ __align__(16) u16 As[BM * BK];
  __shared__ __align__(16) u16 Bs[BN * BK];

  const int tid  = threadIdx.x;
  const int wave = tid >> 6, lane = tid & 63;
  const int wm = wave >> 1, wn = wave & 1;
  const int lr = lane & 15, kg = lane >> 4;

  // XCD-aware bijective swizzle (nwg % 8 == 0 for all our grids)
  const int nwg = gridDim.x * gridDim.y;
  const int h   = blockIdx.y * gridDim.x + blockIdx.x;
  const int cpx = nwg >> 3;
  const int tl  = (h & 7) * cpx + (h >> 3);
  const int bx  = tl % gridDim.x;
  const int by  = tl / gridDim.x;

  const int m0 = bx * BM, n0 = by * BN;

  floatx4 acc[4][FN];
#pragma unroll
  for (int i = 0; i < 4; ++i)
#pragma unroll
    for (int j = 0; j < FN; ++j) acc[i][j] = (floatx4){0.f, 0.f, 0.f, 0.f};

  for (int k0 = 0; k0 < K; k0 += BK) {
#pragma unroll
    for (int ch = 0; ch < (BM * BK / 8) / 256; ++ch) {
      int idx = ch * 256 + tid;
      int row = idx >> 2, kk = (idx & 3) << 3;
      GLDS(A + (size_t)(m0 + row) * K + (k0 + kk), &As[idx * 8]);
    }
#pragma unroll
    for (int ch = 0; ch < (BN * BK / 8) / 256; ++ch) {
      int idx = ch * 256 + tid;
      int row = idx >> 2, kk = (idx & 3) << 3;
      const int bt = n0 + row;
      const u16* src;
      if constexpr (TAPK == 0) {
        src = Bsrc + (size_t)bt * K + (k0 + kk);
      } else {
        const int tap = k0 / TAPK, off = k0 - tap * TAPK;
        const int b = bt >> 10, t = bt & 1023;
        src = Bsrc + ((size_t)(b * 1026 + t + tap)) * TAPK + off + kk;
      }
      GLDS(src, &Bs[idx * 8]);
    }
    __syncthreads();
    bf16x8 af[4], bfr[FN];
#pragma unroll
    for (int i = 0; i < 4; ++i)
      af[i] = *(const bf16x8*)&As[(wm * 64 + i * 16 + lr) * BK + kg * 8];
#pragma unroll
    for (int j = 0; j < FN; ++j)
      bfr[j] = *(const bf16x8*)&Bs[(wn * (BN / 2) + j * 16 + lr) * BK + kg * 8];
#pragma unroll
    for (int i = 0; i < 4; ++i)
#pragma unroll
      for (int j = 0; j < FN; ++j)
        acc[i][j] = __builtin_amdgcn_mfma_f32_16x16x32_bf16(af[i], bfr[j], acc[i][j], 0, 0, 0);
    __syncthreads();
  }

  const int wrow0 = m0 + wm * 64;
  const int col0  = n0 + wn * (BN / 2);

  if constexpr (MODE == 0) {  // ---- QKV: bias + RoPE + scatter ----
    float v[4][FN][4];
#pragma unroll
    for (int i = 0; i < 4; ++i)
#pragma unroll
      for (int j = 0; j < FN; ++j)
#pragma unroll
        for (int r = 0; r < 4; ++r)
          v[i][j][r] = acc[i][j][r] + bias[wrow0 + i * 16 + kg * 4 + r];
    const int sec = wrow0 >> 9;            // 0=q 1=k 2=v
    const int hh  = (wrow0 & 511) >> 6;    // head
    if (sec < 2) {
#pragma unroll
      for (int j = 0; j < FN; ++j) {
        const int t = (col0 + j * 16 + lr) & 1023;
#pragma unroll
        for (int r = 0; r < 4; ++r) {
          const int a = kg * 4 + r;
          const float cv = ctab[t * 16 + a], sv = stab[t * 16 + a];
          const float a0 = v[0][j][r], a1 = v[1][j][r];
          v[0][j][r] = a0 * cv - a1 * sv;
          v[1][j][r] = a1 * cv + a0 * sv;
        }
      }
      u16* dst = (sec == 0) ? o0 : o1;     // q,k: (B,H,T,64)
#pragma unroll
      for (int i = 0; i < 4; ++i)
#pragma unroll
        for (int j = 0; j < FN; ++j) {
          const int bt = col0 + j * 16 + lr;
          const int b = bt >> 10, t = bt & 1023;
          ushort4v pk;
#pragma unroll
          for (int r = 0; r < 4; ++r) pk[r] = f2bf(v[i][j][r]);
          *(ushort4v*)&dst[(((size_t)b * 8 + hh) * 1024 + t) * 64 + i * 16 + kg * 4] = pk;
        }
    } else {                               // v: (B,H,64,T)
#pragma unroll
      for (int i = 0; i < 4; ++i)
#pragma unroll
        for (int j = 0; j < FN; ++j) {
          const int bt = col0 + j * 16 + lr;
          const int b = bt >> 10, t = bt & 1023;
#pragma unroll
          for (int r = 0; r < 4; ++r) {
            const int dk = i * 16 + kg * 4 + r;
            o2[(((size_t)b * 8 + hh) * 64 + dk) * 1024 + t] = f2bf(v[i][j][r]);
          }
        }
    }
  } else if constexpr (MODE == 3) {  // ---- O-proj: +bias -> y (B,C,T) bf16 ----
#pragma unroll
    for (int i = 0; i < 4; ++i)
#pragma unroll
      for (int j = 0; j < FN; ++j) {
        const int bt = col0 + j * 16 + lr;
        const int b = bt >> 10, t = bt & 1023;
#pragma unroll
        for (int r = 0; r < 4; ++r) {
          const int rr = wrow0 + i * 16 + kg * 4 + r;
          o0[((size_t)b * 512 + rr) * 1024 + t] = f2bf(acc[i][j][r] + bias[rr]);
        }
      }
  } else if constexpr (MODE == 4) {  // ---- conv1: relu(acc+b1)*mask -> h1pad ----
#pragma unroll
    for (int i = 0; i < 4; ++i) {
      const int r0 = wrow0 + i * 16 + kg * 4;
#pragma unroll
      for (int j = 0; j < FN; ++j) {
        const int bt = col0 + j * 16 + lr;
        const int b = bt >> 10, t = bt & 1023;
        const float mv = msk[(size_t)b * 1024 + t];
        ushort4v pk;
#pragma unroll
        for (int r = 0; r < 4; ++r)
          pk[r] = f2bf(fmaxf(acc[i][j][r] + bias[r0 + r], 0.f) * mv);
        *(ushort4v*)&o0[((size_t)(b * 1026 + t + 1)) * 2048 + r0] = pk;
      }
    }
  } else {                           // ---- conv2: (acc+b2)*mask -> y (B,C,T) ----
#pragma unroll
    for (int i = 0; i < 4; ++i)
#pragma unroll
      for (int j = 0; j < FN; ++j) {
        const int bt = col0 + j * 16 + lr;
        const int b = bt >> 10, t = bt & 1023;
        const float mv = msk[(size_t)b * 1024 + t];
#pragma unroll
        for (int r = 0; r < 4; ++r) {
          const int rr = wrow0 + i * 16 + kg * 4 + r;
          o0[((size_t)b * 512 + rr) * 1024 + t] = f2bf((acc[i][j][r] + bias[rr]) * mv);
        }
      }
  }
}

// ---------------------------------------------------------------------------
// glue kernels
// ---------------------------------------------------------------------------
__global__ __launch_bounds__(256) void k_cvt(const float* __restrict__ in, u16* __restrict__ out, int n) {
  int i = blockIdx.x * 256 + threadIdx.x;
  if (i < n) out[i] = f2bf(in[i]);
}

__global__ __launch_bounds__(256) void k_repack_w1(const float* __restrict__ in, u16* __restrict__ out) {
  int i = blockIdx.x * 256 + threadIdx.x;          // over 2048*1536
  int f = i / 1536, rem = i % 1536;
  int kk = rem >> 9, c = rem & 511;                // out (F, KS, C)
  out[i] = f2bf(in[f * 1536 + c * 3 + kk]);
}

__global__ __launch_bounds__(256) void k_repack_w2(const float* __restrict__ in, u16* __restrict__ out) {
  int i = blockIdx.x * 256 + threadIdx.x;          // over 512*6144
  int c = i / 6144, rem = i % 6144;
  int kk = rem >> 11, f = rem & 2047;              // out (C, KS, F)
  out[i] = f2bf(in[c * 6144 + f * 3 + kk]);
}

__global__ __launch_bounds__(256) void k_bias_concat(const float* __restrict__ bq, const float* __restrict__ bk,
                                                     const float* __restrict__ bv, float* __restrict__ out) {
  int i = blockIdx.x * 256 + threadIdx.x;
  if (i < 512) out[i] = bq[i];
  else if (i < 1024) out[i] = bk[i - 512];
  else if (i < 1536) out[i] = bv[i - 1024];
}

__global__ __launch_bounds__(256) void k_rope_tables(float* __restrict__ ct, float* __restrict__ st) {
  int i = blockIdx.x * 256 + threadIdx.x;          // 1024*16
  int t = i >> 4, a = i & 15;
  float theta = powf(10000.f, -(float)a / 16.f);
  float ang = (float)t * theta;
  ct[i] = cosf(ang);
  st[i] = sinf(ang);
}

// zero pad rows (row 0 and 1025 of each batch) of a (B,1026,R) bf16 buffer
__global__ __launch_bounds__(256) void k_zrows(u16* __restrict__ p, int R) {
  const int b = blockIdx.x >> 1;
  const size_t row = (blockIdx.x & 1) ? 1025 : 0;
  u16* r = p + ((size_t)b * 1026 + row) * R;
  for (int i = threadIdx.x; i < R; i += 256) r[i] = 0;
}

// tiled fp32 (B,R,TT) -> bf16 (B, padR, R) transpose-convert at row offset ro,
// optional column mask
__global__ __launch_bounds__(256) void k_tcvt(const float* __restrict__ in, u16* __restrict__ out,
                                              const float* __restrict__ msk, int R, int TT,
                                              int padR, int ro) {
  __shared__ u16 tile[64][65];
  const int b = blockIdx.z;
  const int r0 = blockIdx.x * 64, t0 = blockIdx.y * 64;
  const int tx = threadIdx.x & 63, ty = threadIdx.x >> 6;
  const float mv = msk ? msk[(size_t)b * TT + t0 + tx] : 1.f;
  const float* ib = in + (size_t)b * R * TT;
#pragma unroll
  for (int rr = ty; rr < 64; rr += 4)
    tile[rr][tx] = f2bf(ib[(size_t)(r0 + rr) * TT + t0 + tx] * mv);
  __syncthreads();
  u16* ob = out + (size_t)b * padR * R;
#pragma unroll
  for (int tt = ty; tt < 64; tt += 4)
    ob[(size_t)(t0 + tt + ro) * R + r0 + tx] = tile[tx][tt];
}

// in-place row softmax on bf16 scores; one block per row of 1024
__global__ __launch_bounds__(256) void k_softmax(u16* __restrict__ s) {
  const size_t base = (size_t)blockIdx.x * 1024;
  const int tid = threadIdx.x, lane = tid & 63, wv = tid >> 6;
  ushort4v u = *(const ushort4v*)&s[base + tid * 4];
  float v0 = bf2f(u[0]), v1 = bf2f(u[1]), v2 = bf2f(u[2]), v3 = bf2f(u[3]);
  float mx = fmaxf(fmaxf(v0, v1), fmaxf(v2, v3));
#pragma unroll
  for (int o = 32; o; o >>= 1) mx = fmaxf(mx, __shfl_xor(mx, o));
  __shared__ float rmax[4], rsum[4];
  if (lane == 0) rmax[wv] = mx;
  __syncthreads();
  mx = fmaxf(fmaxf(rmax[0], rmax[1]), fmaxf(rmax[2], rmax[3]));
  const float L2E = 1.44269504f;
  float e0 = exp2f((v0 - mx) * L2E), e1 = exp2f((v1 - mx) * L2E);
  float e2 = exp2f((v2 - mx) * L2E), e3 = exp2f((v3 - mx) * L2E);
  float sm = e0 + e1 + e2 + e3;
#pragma unroll
  for (int o = 32; o; o >>= 1) sm += __shfl_xor(sm, o);
  if (lane == 0) rsum[wv] = sm;
  __syncthreads();
  sm = rsum[0] + rsum[1] + rsum[2] + rsum[3];
  const float inv = 1.f / sm;
  ushort4v p;
  p[0] = f2bf(e0 * inv); p[1] = f2bf(e1 * inv); p[2] = f2bf(e2 * inv); p[3] = f2bf(e3 * inv);
  *(ushort4v*)&s[base + tid * 4] = p;
}

// layernorm over C=512 at each (b,t); xin fp32 (B,C,T) [*mask], + ybf bf16 (B,C,T)
__global__ __launch_bounds__(256) void k_ln(const float* __restrict__ xin, const u16* __restrict__ ybf,
                                            const float* __restrict__ xm, const float* __restrict__ g,
                                            const float* __restrict__ be, float* __restrict__ xout) {
  const int b = blockIdx.x;
  const int tx = threadIdx.x & 63, ty = threadIdx.x >> 6;
  const int t = blockIdx.y * 64 + tx;
  const float m = xm ? xm[(size_t)b * 1024 + t] : 1.f;
  const size_t base = (size_t)b * 512 * 1024 + t;
  float sum = 0.f, ss = 0.f;
  for (int c = ty; c < 512; c += 4) {
    float r = xin[base + (size_t)c * 1024] * m + bf2f(ybf[base + (size_t)c * 1024]);
    sum += r; ss += r * r;
  }
  __shared__ float S[4][64], Q[4][64];
  S[ty][tx] = sum; Q[ty][tx] = ss;
  __syncthreads();
  sum = S[0][tx] + S[1][tx] + S[2][tx] + S[3][tx];
  ss  = Q[0][tx] + Q[1][tx] + Q[2][tx] + Q[3][tx];
  const float mean = sum * (1.f / 512.f);
  const float var  = ss * (1.f / 512.f) - mean * mean;
  const float rs   = rsqrtf(var + 1e-4f);
  for (int c = ty; c < 512; c += 4) {
    float r = xin[base + (size_t)c * 1024] * m + bf2f(ybf[base + (size_t)c * 1024]);
    xout[base + (size_t)c * 1024] = (r - mean) * rs * g[c] + be[c];
  }
}

// ---------------------------------------------------------------------------
extern "C" void kernel_launch(void* const* d_in, const int* in_sizes, int n_in,
                              void* d_out, int out_size, void* d_ws, size_t ws_size,
                              hipStream_t stream) {
  (void)in_sizes; (void)n_in; (void)out_size; (void)ws_size;
  const float* x   = (const float*)d_in[0];
  const float* xm  = (const float*)d_in[1];
  const float* am  = (const float*)d_in[2];
  const float* wq  = (const float*)d_in[3];
  const float* bq  = (const float*)d_in[4];
  const float* wk  = (const float*)d_in[5];
  const float* bk  = (const float*)d_in[6];
  const float* wv  = (const float*)d_in[7];
  const float* bv  = (const float*)d_in[8];
  const float* wo  = (const float*)d_in[9];
  const float* bo  = (const float*)d_in[10];
  const float* w1  = (const float*)d_in[11];
  const float* b1  = (const float*)d_in[12];
  const float* w2  = (const float*)d_in[13];
  const float* b2  = (const float*)d_in[14];
  const float* g1  = (const float*)d_in[15];
  const float* be1 = (const float*)d_in[16];
  const float* g2  = (const float*)d_in[17];
  const float* be2 = (const float*)d_in[18];
  float* out = (float*)d_out;

  char* ws = (char*)d_ws;
  size_t off = 0;
  auto alloc = [&](size_t bytes) { char* p = ws + off; off += (bytes + 255) & ~(size_t)255; return p; };

  u16*   wqkv = (u16*)  alloc((size_t)1536 * 512 * 2);
  u16*   wob  = (u16*)  alloc((size_t)512 * 512 * 2);
  u16*   w1p  = (u16*)  alloc((size_t)2048 * 1536 * 2);
  u16*   w2p  = (u16*)  alloc((size_t)512 * 6144 * 2);
  float* bqkv = (float*)alloc(1536 * 4);
  float* ctab = (float*)alloc(1024 * 16 * 4);
  float* stab = (float*)alloc(1024 * 16 * 4);
  float* X2   = (float*)alloc((size_t)8 * 512 * 1024 * 4);   // LN1 output fp32
  u16*   x2p  = (u16*)  alloc((size_t)8 * 1026 * 512 * 2);   // LN1 out ^T, padded, masked
  u16*   h1p  = (u16*)  alloc((size_t)8 * 1026 * 2048 * 2);  // conv1 out, padded (B,1026,F)
  u16*   y    = (u16*)  alloc((size_t)8 * 512 * 1024 * 2);   // y1 then y2 (B,C,T)
  u16*   xbT  = (u16*)  alloc((size_t)8 * 1024 * 512 * 2);   // masked x^T; reused as o^T
  u16*   qkv3 = (u16*)  alloc((size_t)3 * 8 * 8 * 1024 * 64 * 2); // q,k,v
  u16*   sb   = (u16*)  alloc((size_t)8 * 8 * 1024 * 1024 * 2);   // scores / p

  u16* qb = qkv3;
  u16* kb = qkv3 + (size_t)8 * 8 * 1024 * 64;
  u16* vb = kb   + (size_t)8 * 8 * 1024 * 64;
  u16* oT = xbT;

  dim3 blk(256);

  // weight/bias/table prep
  k_cvt<<<dim3(1024), blk, 0, stream>>>(wq, wqkv, 512 * 512);
  k_cvt<<<dim3(1024), blk, 0, stream>>>(wk, wqkv + 512 * 512, 512 * 512);
  k_cvt<<<dim3(1024), blk, 0, stream>>>(wv, wqkv + 2 * 512 * 512, 512 * 512);
  k_cvt<<<dim3(1024), blk, 0, stream>>>(wo, wob, 512 * 512);
  k_repack_w1<<<dim3(12288), blk, 0, stream>>>(w1, w1p);
  k_repack_w2<<<dim3(12288), blk, 0, stream>>>(w2, w2p);
  k_bias_concat<<<dim3(6), blk, 0, stream>>>(bq, bk, bv, bqkv);
  k_rope_tables<<<dim3(64), blk, 0, stream>>>(ctab, stab);
  k_zrows<<<dim3(16), blk, 0, stream>>>(x2p, 512);
  k_zrows<<<dim3(16), blk, 0, stream>>>(h1p, 2048);

  // x^T (masked, bf16, unpadded)
  k_tcvt<<<dim3(8, 16, 8), blk, 0, stream>>>(x, xbT, xm, 512, 1024, 1024, 0);

  // QKV projection + bias + rope + head scatter  (flat N=8192)
  k_cgemm<0, 128, 0><<<dim3(12, 64), blk, 0, stream>>>(
      wqkv, xbT, 512, qb, kb, vb, bqkv, ctab, stab, nullptr);

  // scores = q k^T / 8 (+ mask), bf16
  k_gemm<1, 128><<<dim3(8, 8, 64), blk, 0, stream>>>(
      qb, 64, 65536, kb, 64, 65536, 64, sb, am);

  // softmax rows in place
  k_softmax<<<dim3(65536), blk, 0, stream>>>(sb);

  // o = p v, written as o^T (B,T,C)
  k_gemm<2, 64><<<dim3(8, 1, 64), blk, 0, stream>>>(
      sb, 1024, 1048576, vb, 1024, 65536, 1024, oT, nullptr);

  // y1 = wo o + bo (B,C,T)
  k_cgemm<3, 64, 0><<<dim3(4, 128), blk, 0, stream>>>(
      wob, oT, 512, y, nullptr, nullptr, bo, nullptr, nullptr, nullptr);

  // LN1: X2 = ln(x*mask + y1)
  k_ln<<<dim3(8, 16), blk, 0, stream>>>(x, y, xm, g1, be1, X2);

  // conv path (no im2col: tap-shifted padded activations)
  k_tcvt<<<dim3(8, 16, 8), blk, 0, stream>>>(X2, x2p, xm, 512, 1024, 1026, 1);
  k_cgemm<4, 128, 512><<<dim3(16, 64), blk, 0, stream>>>(
      w1p, x2p, 1536, h1p, nullptr, nullptr, b1, nullptr, nullptr, xm);
  k_cgemm<5, 64, 2048><<<dim3(4, 128), blk, 0, stream>>>(
      w2p, h1p, 6144, y, nullptr, nullptr, b2, nullptr, nullptr, xm);

  // LN2 -> out
  k_ln<<<dim3(8, 16), blk, 0, stream>>>(X2, y, nullptr, g2, be2, out);
}